// Round 1
// baseline (1762.383 us; speedup 1.0000x reference)
//
#include <hip/hip_runtime.h>

#define N_NODES 10000
#define N_EDGES 160000

// ---------------------------------------------------------------------------
// Degree: deg[i] = 1.0 + sum_{e: dst[e]==i} w[e]
// ---------------------------------------------------------------------------
__global__ void k_init_deg(float* __restrict__ deg) {
    int i = blockIdx.x * blockDim.x + threadIdx.x;
    if (i < N_NODES) deg[i] = 1.0f;
}

__global__ void k_accum_deg(const int* __restrict__ dst, const float* __restrict__ w,
                            float* __restrict__ deg) {
    int e = blockIdx.x * blockDim.x + threadIdx.x;
    if (e < N_EDGES) atomicAdd(&deg[dst[e]], w[e]);
}

__global__ void k_norm(const int* __restrict__ src, const int* __restrict__ dst,
                       const float* __restrict__ w, const float* __restrict__ deg,
                       float* __restrict__ norm) {
    int e = blockIdx.x * blockDim.x + threadIdx.x;
    if (e < N_EDGES) {
        norm[e] = rsqrtf(deg[src[e]]) * w[e] * rsqrtf(deg[dst[e]]);
    }
}

// ---------------------------------------------------------------------------
// FP32 tiled GEMM: C[M,N] = A[M,K] * B[K,N], row-major.
// 64x64 tile, BK=32, 256 threads, 4x4 micro-tile per thread.
// N, K must be multiples of 64/32 (they are: 512/256); M bounds-checked.
// ---------------------------------------------------------------------------
__global__ __launch_bounds__(256) void k_gemm(const float* __restrict__ A,
                                              const float* __restrict__ B,
                                              float* __restrict__ C,
                                              int M, int N, int K) {
    const int BK = 32;
    __shared__ float As[BK][68];  // transposed [k][m], padded
    __shared__ float Bs[BK][68];  // [k][n], padded

    int tid = threadIdx.x;
    int tx = tid & 15;        // col group
    int ty = tid >> 4;        // row group
    int row0 = blockIdx.y * 64;
    int col0 = blockIdx.x * 64;

    float acc[4][4];
#pragma unroll
    for (int i = 0; i < 4; i++)
#pragma unroll
        for (int j = 0; j < 4; j++) acc[i][j] = 0.0f;

    for (int k0 = 0; k0 < K; k0 += BK) {
        // load A tile 64 x BK (transpose into As[k][m])
#pragma unroll
        for (int q = tid; q < 64 * BK / 4; q += 256) {
            int r = q >> 3;      // row in tile (BK/4 = 8 float4 per row)
            int c4 = q & 7;
            float4 v = make_float4(0.f, 0.f, 0.f, 0.f);
            int gr = row0 + r;
            if (gr < M) v = *(const float4*)&A[(long long)gr * K + k0 + c4 * 4];
            As[c4 * 4 + 0][r] = v.x;
            As[c4 * 4 + 1][r] = v.y;
            As[c4 * 4 + 2][r] = v.z;
            As[c4 * 4 + 3][r] = v.w;
        }
        // load B tile BK x 64
#pragma unroll
        for (int q = tid; q < BK * 64 / 4; q += 256) {
            int r = q >> 4;      // k row (16 float4 per row)
            int c4 = q & 15;
            float4 v = *(const float4*)&B[(long long)(k0 + r) * N + col0 + c4 * 4];
            *(float4*)&Bs[r][c4 * 4] = v;
        }
        __syncthreads();

#pragma unroll
        for (int k = 0; k < BK; k++) {
            float4 av = *(const float4*)&As[k][ty * 4];
            float4 bv = *(const float4*)&Bs[k][tx * 4];
            float ar[4] = {av.x, av.y, av.z, av.w};
            float br[4] = {bv.x, bv.y, bv.z, bv.w};
#pragma unroll
            for (int i = 0; i < 4; i++)
#pragma unroll
                for (int j = 0; j < 4; j++) acc[i][j] += ar[i] * br[j];
        }
        __syncthreads();
    }

#pragma unroll
    for (int i = 0; i < 4; i++) {
        int gr = row0 + ty * 4 + i;
        if (gr < M) {
            float4 v = make_float4(acc[i][0], acc[i][1], acc[i][2], acc[i][3]);
            *(float4*)&C[(long long)gr * N + col0 + tx * 4] = v;
        }
    }
}

// ---------------------------------------------------------------------------
// Self-loop init: agg[i,f] = h[i,f] / deg[i]
// ---------------------------------------------------------------------------
template <int F>
__global__ void k_selfloop(const float* __restrict__ h, const float* __restrict__ deg,
                           float* __restrict__ agg) {
    const int F4 = F / 4;
    long long idx = (long long)blockIdx.x * blockDim.x + threadIdx.x;
    if (idx < (long long)N_NODES * F4) {
        int i = (int)(idx / F4);
        int f4 = (int)(idx % F4);
        float inv = 1.0f / deg[i];
        float4 v = *(const float4*)&h[(long long)i * F + f4 * 4];
        v.x *= inv; v.y *= inv; v.z *= inv; v.w *= inv;
        *(float4*)&agg[(long long)i * F + f4 * 4] = v;
    }
}

// ---------------------------------------------------------------------------
// Scatter: agg[dst[e], :] += norm[e] * h[src[e], :]
// one thread per (edge, 4 features)
// ---------------------------------------------------------------------------
template <int F>
__global__ void k_scatter(const int* __restrict__ src, const int* __restrict__ dst,
                          const float* __restrict__ norm, const float* __restrict__ h,
                          float* __restrict__ agg) {
    const int F4 = F / 4;
    long long idx = (long long)blockIdx.x * blockDim.x + threadIdx.x;
    if (idx < (long long)N_EDGES * F4) {
        int e = (int)(idx / F4);
        int f4 = (int)(idx % F4);
        int s = src[e];
        int d = dst[e];
        float nw = norm[e];
        float4 v = *(const float4*)&h[(long long)s * F + f4 * 4];
        float* out = &agg[(long long)d * F + f4 * 4];
        atomicAdd(out + 0, nw * v.x);
        atomicAdd(out + 1, nw * v.y);
        atomicAdd(out + 2, nw * v.z);
        atomicAdd(out + 3, nw * v.w);
    }
}

// ---------------------------------------------------------------------------
// ReLU: out[i] = max(in[i], 0)
// ---------------------------------------------------------------------------
__global__ void k_relu(const float* __restrict__ in, float* __restrict__ out, long long n4) {
    long long idx = (long long)blockIdx.x * blockDim.x + threadIdx.x;
    if (idx < n4) {
        float4 v = *(const float4*)&in[idx * 4];
        v.x = fmaxf(v.x, 0.f); v.y = fmaxf(v.y, 0.f);
        v.z = fmaxf(v.z, 0.f); v.w = fmaxf(v.w, 0.f);
        *(float4*)&out[idx * 4] = v;
    }
}

// ---------------------------------------------------------------------------
extern "C" void kernel_launch(void* const* d_in, const int* in_sizes, int n_in,
                              void* d_out, int out_size, void* d_ws, size_t ws_size,
                              hipStream_t stream) {
    const float* x  = (const float*)d_in[0];                 // [10000, 512]
    const int*   ei = (const int*)d_in[1];                   // [2, 160000]
    const float* w  = (const float*)d_in[2];                 // [160000]
    const float* W1 = (const float*)d_in[3];                 // [512, 512]
    const float* W2 = (const float*)d_in[4];                 // [512, 256]
    float* out = (float*)d_out;                              // [10000, 256]

    const int* src = ei;
    const int* dst = ei + N_EDGES;

    // workspace layout (floats)
    float* ws = (float*)d_ws;
    float* h1   = ws;                         // [10000, 512] (reused as hfin after relu)
    float* agg1 = h1 + (long long)N_NODES * 512;   // [10000, 512]
    float* h2   = agg1 + (long long)N_NODES * 512; // [10000, 256]
    float* deg  = h2 + (long long)N_NODES * 256;   // [10000]
    float* norm = deg + N_NODES;                   // [160000]

    const int B = 256;

    // degree + norm
    k_init_deg<<<(N_NODES + B - 1) / B, B, 0, stream>>>(deg);
    k_accum_deg<<<(N_EDGES + B - 1) / B, B, 0, stream>>>(dst, w, deg);
    k_norm<<<(N_EDGES + B - 1) / B, B, 0, stream>>>(src, dst, w, deg, norm);

    // layer 1: h1 = x @ W1
    {
        dim3 grid(512 / 64, (N_NODES + 63) / 64);
        k_gemm<<<grid, 256, 0, stream>>>(x, W1, h1, N_NODES, 512, 512);
    }
    // agg1 = h1/deg + scatter(norm * h1[src])
    k_selfloop<512><<<(N_NODES * 128 + B - 1) / B, B, 0, stream>>>(h1, deg, agg1);
    k_scatter<512><<<((long long)N_EDGES * 128 + B - 1) / B, B, 0, stream>>>(src, dst, norm, h1, agg1);
    // hfin = relu(agg1) -> write into h1 buffer
    k_relu<<<((long long)N_NODES * 512 / 4 + B - 1) / B, B, 0, stream>>>(agg1, h1, (long long)N_NODES * 512 / 4);

    // layer 2: h2 = hfin @ W2
    {
        dim3 grid(256 / 64, (N_NODES + 63) / 64);
        k_gemm<<<grid, 256, 0, stream>>>(h1, W2, h2, N_NODES, 256, 512);
    }
    // out = h2/deg + scatter(norm * h2[src])
    k_selfloop<256><<<(N_NODES * 64 + B - 1) / B, B, 0, stream>>>(h2, deg, out);
    k_scatter<256><<<((long long)N_EDGES * 64 + B - 1) / B, B, 0, stream>>>(src, dst, norm, h2, out);
}

// Round 2
// 243.797 us; speedup vs baseline: 7.2289x; 7.2289x over previous
//
#include <hip/hip_runtime.h>

#define N_NODES 10000
#define N_EDGES 160000

// ---------------------------------------------------------------------------
// init: deg[i] = 1.0 (self-loop), count[i] = 0
// ---------------------------------------------------------------------------
__global__ void k_init(float* __restrict__ deg, int* __restrict__ count) {
    int i = blockIdx.x * blockDim.x + threadIdx.x;
    if (i < N_NODES) { deg[i] = 1.0f; count[i] = 0; }
}

// deg[dst] += w, count[dst] += 1
__global__ void k_deg_count(const int* __restrict__ dst, const float* __restrict__ w,
                            float* __restrict__ deg, int* __restrict__ count) {
    int e = blockIdx.x * blockDim.x + threadIdx.x;
    if (e < N_EDGES) {
        int d = dst[e];
        atomicAdd(&deg[d], w[e]);
        atomicAdd(&count[d], 1);
    }
}

// ---------------------------------------------------------------------------
// exclusive scan of count[0..N) -> row_ptr[0..N], cursor = copy of row_ptr
// single block, 1024 threads, 10 elements/thread
// ---------------------------------------------------------------------------
__global__ __launch_bounds__(1024) void k_scan(const int* __restrict__ count,
                                               int* __restrict__ row_ptr,
                                               int* __restrict__ cursor) {
    __shared__ int sums[1024];
    const int CH = 10;  // 1024*10 >= 10000
    int t = threadIdx.x;
    int base = t * CH;
    int c[CH];
    int local = 0;
#pragma unroll
    for (int j = 0; j < CH; j++) {
        int i = base + j;
        c[j] = (i < N_NODES) ? count[i] : 0;
        local += c[j];
    }
    sums[t] = local;
    __syncthreads();
    // Hillis-Steele inclusive scan
    for (int off = 1; off < 1024; off <<= 1) {
        int v = sums[t];
        int u = (t >= off) ? sums[t - off] : 0;
        __syncthreads();
        sums[t] = v + u;
        __syncthreads();
    }
    int excl = sums[t] - local;
#pragma unroll
    for (int j = 0; j < CH; j++) {
        int i = base + j;
        if (i < N_NODES) {
            row_ptr[i] = excl;
            cursor[i] = excl;
            excl += c[j];
        }
    }
    if (t == 1023) row_ptr[N_NODES] = sums[1023];
}

// ---------------------------------------------------------------------------
// fill CSR: for each edge, pos = cursor[dst]++; csr_src[pos]=src;
// csr_norm[pos] = d^-1/2[src] * w * d^-1/2[dst]
// ---------------------------------------------------------------------------
__global__ void k_fill(const int* __restrict__ src, const int* __restrict__ dst,
                       const float* __restrict__ w, const float* __restrict__ deg,
                       int* __restrict__ cursor, int* __restrict__ csr_src,
                       float* __restrict__ csr_norm) {
    int e = blockIdx.x * blockDim.x + threadIdx.x;
    if (e < N_EDGES) {
        int d = dst[e];
        int s = src[e];
        int pos = atomicAdd(&cursor[d], 1);
        csr_src[pos] = s;
        csr_norm[pos] = rsqrtf(deg[s]) * w[e] * rsqrtf(deg[d]);
    }
}

// ---------------------------------------------------------------------------
// FP32 tiled GEMM: C[M,N] = A[M,K] * B[K,N], row-major.
// 64x64 tile, BK=32, 256 threads, 4x4 micro-tile per thread.
// ---------------------------------------------------------------------------
__global__ __launch_bounds__(256) void k_gemm(const float* __restrict__ A,
                                              const float* __restrict__ B,
                                              float* __restrict__ C,
                                              int M, int N, int K) {
    const int BK = 32;
    __shared__ float As[BK][68];
    __shared__ float Bs[BK][68];

    int tid = threadIdx.x;
    int tx = tid & 15;
    int ty = tid >> 4;
    int row0 = blockIdx.y * 64;
    int col0 = blockIdx.x * 64;

    float acc[4][4];
#pragma unroll
    for (int i = 0; i < 4; i++)
#pragma unroll
        for (int j = 0; j < 4; j++) acc[i][j] = 0.0f;

    for (int k0 = 0; k0 < K; k0 += BK) {
#pragma unroll
        for (int q = tid; q < 64 * BK / 4; q += 256) {
            int r = q >> 3;
            int c4 = q & 7;
            float4 v = make_float4(0.f, 0.f, 0.f, 0.f);
            int gr = row0 + r;
            if (gr < M) v = *(const float4*)&A[(long long)gr * K + k0 + c4 * 4];
            As[c4 * 4 + 0][r] = v.x;
            As[c4 * 4 + 1][r] = v.y;
            As[c4 * 4 + 2][r] = v.z;
            As[c4 * 4 + 3][r] = v.w;
        }
#pragma unroll
        for (int q = tid; q < BK * 64 / 4; q += 256) {
            int r = q >> 4;
            int c4 = q & 15;
            float4 v = *(const float4*)&B[(long long)(k0 + r) * N + col0 + c4 * 4];
            *(float4*)&Bs[r][c4 * 4] = v;
        }
        __syncthreads();

#pragma unroll
        for (int k = 0; k < BK; k++) {
            float4 av = *(const float4*)&As[k][ty * 4];
            float4 bv = *(const float4*)&Bs[k][tx * 4];
            float ar[4] = {av.x, av.y, av.z, av.w};
            float br[4] = {bv.x, bv.y, bv.z, bv.w};
#pragma unroll
            for (int i = 0; i < 4; i++)
#pragma unroll
                for (int j = 0; j < 4; j++) acc[i][j] += ar[i] * br[j];
        }
        __syncthreads();
    }

#pragma unroll
    for (int i = 0; i < 4; i++) {
        int gr = row0 + ty * 4 + i;
        if (gr < M) {
            float4 v = make_float4(acc[i][0], acc[i][1], acc[i][2], acc[i][3]);
            *(float4*)&C[(long long)gr * N + col0 + tx * 4] = v;
        }
    }
}

// ---------------------------------------------------------------------------
// CSR gather aggregation: one wave (64 lanes) per node.
// out[i,:] = h[i,:]/deg[i] + sum_p csr_norm[p] * h[csr_src[p],:]
// optional fused ReLU.
// ---------------------------------------------------------------------------
template <int F, bool RELU>
__global__ __launch_bounds__(256) void k_gather(const int* __restrict__ csr_src,
                                                const float* __restrict__ csr_norm,
                                                const int* __restrict__ row_ptr,
                                                const float* __restrict__ h,
                                                const float* __restrict__ deg,
                                                float* __restrict__ out) {
    const int FPT = F / 64;  // floats per lane (8 for F=512, 4 for F=256)
    int wave = (int)((blockIdx.x * (long long)blockDim.x + threadIdx.x) >> 6);
    if (wave >= N_NODES) return;
    int lane = threadIdx.x & 63;
    const long long off = (long long)wave * F + lane * FPT;

    float acc[FPT];
    float inv = 1.0f / deg[wave];
#pragma unroll
    for (int j = 0; j < FPT; j += 4) {
        float4 v = *(const float4*)&h[off + j];
        acc[j] = v.x * inv; acc[j + 1] = v.y * inv;
        acc[j + 2] = v.z * inv; acc[j + 3] = v.w * inv;
    }

    int p = row_ptr[wave];
    int p1 = row_ptr[wave + 1];
    // 2 edges per iteration for memory-level parallelism
    for (; p + 1 < p1; p += 2) {
        int s0 = csr_src[p];
        int s1 = csr_src[p + 1];
        float n0 = csr_norm[p];
        float n1 = csr_norm[p + 1];
        const float* h0 = &h[(long long)s0 * F + lane * FPT];
        const float* h1 = &h[(long long)s1 * F + lane * FPT];
#pragma unroll
        for (int j = 0; j < FPT; j += 4) {
            float4 a = *(const float4*)&h0[j];
            float4 b = *(const float4*)&h1[j];
            acc[j]     += n0 * a.x + n1 * b.x;
            acc[j + 1] += n0 * a.y + n1 * b.y;
            acc[j + 2] += n0 * a.z + n1 * b.z;
            acc[j + 3] += n0 * a.w + n1 * b.w;
        }
    }
    if (p < p1) {
        int s0 = csr_src[p];
        float n0 = csr_norm[p];
        const float* h0 = &h[(long long)s0 * F + lane * FPT];
#pragma unroll
        for (int j = 0; j < FPT; j += 4) {
            float4 a = *(const float4*)&h0[j];
            acc[j]     += n0 * a.x;
            acc[j + 1] += n0 * a.y;
            acc[j + 2] += n0 * a.z;
            acc[j + 3] += n0 * a.w;
        }
    }

#pragma unroll
    for (int j = 0; j < FPT; j += 4) {
        float4 v = make_float4(acc[j], acc[j + 1], acc[j + 2], acc[j + 3]);
        if (RELU) {
            v.x = fmaxf(v.x, 0.f); v.y = fmaxf(v.y, 0.f);
            v.z = fmaxf(v.z, 0.f); v.w = fmaxf(v.w, 0.f);
        }
        *(float4*)&out[off + j] = v;
    }
}

// ---------------------------------------------------------------------------
extern "C" void kernel_launch(void* const* d_in, const int* in_sizes, int n_in,
                              void* d_out, int out_size, void* d_ws, size_t ws_size,
                              hipStream_t stream) {
    const float* x  = (const float*)d_in[0];                 // [10000, 512]
    const int*   ei = (const int*)d_in[1];                   // [2, 160000]
    const float* w  = (const float*)d_in[2];                 // [160000]
    const float* W1 = (const float*)d_in[3];                 // [512, 512]
    const float* W2 = (const float*)d_in[4];                 // [512, 256]
    float* out = (float*)d_out;                              // [10000, 256]

    const int* src = ei;
    const int* dst = ei + N_EDGES;

    // workspace layout
    float* ws = (float*)d_ws;
    float* h1       = ws;                                    // [10000,512]
    float* agg1     = h1 + (long long)N_NODES * 512;         // [10000,512] (relu'd)
    float* h2       = agg1 + (long long)N_NODES * 512;       // [10000,256]
    float* deg      = h2 + (long long)N_NODES * 256;         // [10000]
    float* csr_norm = deg + N_NODES;                         // [160000]
    int*   csr_src  = (int*)(csr_norm + N_EDGES);            // [160000]
    int*   count    = csr_src + N_EDGES;                     // [10000]
    int*   row_ptr  = count + N_NODES;                       // [10001]
    int*   cursor   = row_ptr + N_NODES + 1;                 // [10000]

    const int B = 256;

    // ---- build normalization + CSR (by dst) ----
    k_init<<<(N_NODES + B - 1) / B, B, 0, stream>>>(deg, count);
    k_deg_count<<<(N_EDGES + B - 1) / B, B, 0, stream>>>(dst, w, deg, count);
    k_scan<<<1, 1024, 0, stream>>>(count, row_ptr, cursor);
    k_fill<<<(N_EDGES + B - 1) / B, B, 0, stream>>>(src, dst, w, deg, cursor, csr_src, csr_norm);

    // ---- layer 1: h1 = x @ W1 ----
    {
        dim3 grid(512 / 64, (N_NODES + 63) / 64);
        k_gemm<<<grid, 256, 0, stream>>>(x, W1, h1, N_NODES, 512, 512);
    }
    // agg1 = relu(gather(h1))
    k_gather<512, true><<<(N_NODES * 64 + B - 1) / B, B, 0, stream>>>(
        csr_src, csr_norm, row_ptr, h1, deg, agg1);

    // ---- layer 2: h2 = agg1 @ W2 ----
    {
        dim3 grid(256 / 64, (N_NODES + 63) / 64);
        k_gemm<<<grid, 256, 0, stream>>>(agg1, W2, h2, N_NODES, 256, 512);
    }
    // out = gather(h2)
    k_gather<256, false><<<(N_NODES * 64 + B - 1) / B, B, 0, stream>>>(
        csr_src, csr_norm, row_ptr, h2, deg, out);
}

// Round 3
// 136.433 us; speedup vs baseline: 12.9175x; 1.7869x over previous
//
#include <hip/hip_runtime.h>

#define N_NODES 10000
#define N_EDGES 160000
#define M_PAD   10112   // 79 * 128
#define MT      79
#define KT      8       // K = 512 = 8 * 64

typedef short s8v __attribute__((ext_vector_type(8)));
typedef short s4v __attribute__((ext_vector_type(4)));
typedef float f4v __attribute__((ext_vector_type(4)));

__device__ inline short f2bf(float f) {
    unsigned u = __builtin_bit_cast(unsigned, f);
    u += 0x7FFF + ((u >> 16) & 1);   // RTNE
    return (short)(u >> 16);
}
__device__ inline float bf2f(short s) {
    return __builtin_bit_cast(float, ((unsigned)(unsigned short)s) << 16);
}

#define GLD_LDS16(g, l)                                                      \
    __builtin_amdgcn_global_load_lds(                                        \
        (const __attribute__((address_space(1))) unsigned int*)(g),          \
        (__attribute__((address_space(3))) unsigned int*)(l), 16, 0, 0)

// ---------------------------------------------------------------------------
// degree / CSR build
// ---------------------------------------------------------------------------
__global__ void k_init(float* __restrict__ deg, int* __restrict__ count) {
    int i = blockIdx.x * blockDim.x + threadIdx.x;
    if (i < N_NODES) { deg[i] = 1.0f; count[i] = 0; }
}

__global__ void k_deg_count(const int* __restrict__ dst, const float* __restrict__ w,
                            float* __restrict__ deg, int* __restrict__ count) {
    int e = blockIdx.x * blockDim.x + threadIdx.x;
    if (e < N_EDGES) {
        int d = dst[e];
        atomicAdd(&deg[d], w[e]);
        atomicAdd(&count[d], 1);
    }
}

__global__ __launch_bounds__(1024) void k_scan(const int* __restrict__ count,
                                               int* __restrict__ row_ptr,
                                               int* __restrict__ cursor) {
    __shared__ int sums[1024];
    const int CH = 10;
    int t = threadIdx.x;
    int base = t * CH;
    int c[CH];
    int local = 0;
#pragma unroll
    for (int j = 0; j < CH; j++) {
        int i = base + j;
        c[j] = (i < N_NODES) ? count[i] : 0;
        local += c[j];
    }
    sums[t] = local;
    __syncthreads();
    for (int off = 1; off < 1024; off <<= 1) {
        int v = sums[t];
        int u = (t >= off) ? sums[t - off] : 0;
        __syncthreads();
        sums[t] = v + u;
        __syncthreads();
    }
    int excl = sums[t] - local;
#pragma unroll
    for (int j = 0; j < CH; j++) {
        int i = base + j;
        if (i < N_NODES) {
            row_ptr[i] = excl;
            cursor[i] = excl;
            excl += c[j];
        }
    }
    if (t == 1023) row_ptr[N_NODES] = sums[1023];
}

__global__ void k_fill(const int* __restrict__ src, const int* __restrict__ dst,
                       const float* __restrict__ w, const float* __restrict__ deg,
                       int* __restrict__ cursor, int* __restrict__ csr_src,
                       float* __restrict__ csr_norm) {
    int e = blockIdx.x * blockDim.x + threadIdx.x;
    if (e < N_EDGES) {
        int d = dst[e];
        int s = src[e];
        int pos = atomicAdd(&cursor[d], 1);
        csr_src[pos] = s;
        csr_norm[pos] = rsqrtf(deg[s]) * w[e] * rsqrtf(deg[d]);
    }
}

// ---------------------------------------------------------------------------
// fp32 -> bf16 conversions into GEMM-ready tiled+swizzled layout.
// Tile image = 16 KiB: [128 rows][64 k] bf16, row = 128 B = 8 chunks of 16 B,
// chunk at (r, slot) holds elements k = (slot ^ (r&7))*8 .. +8.
// Buffer layout: [row_tile][k_tile][16384 bytes].
// ---------------------------------------------------------------------------
__global__ void k_cvt_x(const float* __restrict__ x, char* __restrict__ out) {
    long long t = (long long)blockIdx.x * blockDim.x + threadIdx.x;
    if (t >= (long long)M_PAD * 64) return;
    int gr = (int)(t >> 6);
    int c  = (int)(t & 63);          // 16B chunk within the 512-col row
    s8v v;
    if (gr < N_NODES) {
        const float* p = &x[(long long)gr * 512 + c * 8];
#pragma unroll
        for (int j = 0; j < 8; j++) v[j] = f2bf(p[j]);
    } else {
#pragma unroll
        for (int j = 0; j < 8; j++) v[j] = 0;
    }
    int r = gr & 127, tm = gr >> 7, tk = c >> 3, sc = c & 7;
    int slot = sc ^ (r & 7);
    *(s8v*)&out[(((long long)tm * KT + tk) << 14) + r * 128 + slot * 16] = v;
}

// W [512][NCOLS] fp32 -> W^T bf16 tiled: [NCOLS/128][KT][16384]
template <int NCOLS>
__global__ void k_cvt_w(const float* __restrict__ W, char* __restrict__ out) {
    int t = blockIdx.x * blockDim.x + threadIdx.x;
    if (t >= NCOLS * 64) return;
    int n = t >> 6;
    int c = t & 63;                  // k-chunk index (8 k each)
    s8v v;
#pragma unroll
    for (int j = 0; j < 8; j++) v[j] = f2bf(W[(long long)(c * 8 + j) * NCOLS + n]);
    int r = n & 127, tn = n >> 7, tk = c >> 3, sc = c & 7;
    int slot = sc ^ (r & 7);
    *(s8v*)&out[(((long long)tn * KT + tk) << 14) + r * 128 + slot * 16] = v;
}

// ---------------------------------------------------------------------------
// bf16 MFMA GEMM: C[M,N] (bf16 out) = A[M,K] * B[K,N]
// A, B given as tiled+swizzled bf16 images (B as B^T tiles).
// 128x128 tile, BK=64, 256 threads = 4 waves (2x2), wave tile 64x64.
// ---------------------------------------------------------------------------
__global__ __launch_bounds__(256) void k_gemm_bf16(const char* __restrict__ A,
                                                   const char* __restrict__ B,
                                                   short* __restrict__ Cb,
                                                   int M, int N) {
    __shared__ char As[16384];
    __shared__ char Bs[16384];
    int tid = threadIdx.x, lane = tid & 63, w = tid >> 6;
    int wr = w >> 1, wc = w & 1;

    const char* ga = A + ((long long)blockIdx.y * KT << 14);
    const char* gb = B + ((long long)blockIdx.x * KT << 14);

    f4v acc[4][4];
#pragma unroll
    for (int m = 0; m < 4; m++)
#pragma unroll
        for (int n = 0; n < 4; n++) acc[m][n] = (f4v){0.f, 0.f, 0.f, 0.f};

    for (int kt = 0; kt < KT; ++kt) {
        const char* a0 = ga + (kt << 14);
        const char* b0 = gb + (kt << 14);
#pragma unroll
        for (int j = 0; j < 4; ++j) {
            int off = (j * 256 + w * 64) * 16;   // wave-uniform LDS base
            GLD_LDS16(a0 + off + lane * 16, As + off);
            GLD_LDS16(b0 + off + lane * 16, Bs + off);
        }
        __syncthreads();   // drains vmcnt before barrier

#pragma unroll
        for (int kk = 0; kk < 2; ++kk) {
            s8v a[4], b[4];
#pragma unroll
            for (int m = 0; m < 4; ++m) {
                int r = wr * 64 + m * 16 + (lane & 15);
                int slot = ((lane >> 4) + kk * 4) ^ (r & 7);
                a[m] = *(const s8v*)&As[r * 128 + slot * 16];
            }
#pragma unroll
            for (int n = 0; n < 4; ++n) {
                int r = wc * 64 + n * 16 + (lane & 15);
                int slot = ((lane >> 4) + kk * 4) ^ (r & 7);
                b[n] = *(const s8v*)&Bs[r * 128 + slot * 16];
            }
#pragma unroll
            for (int m = 0; m < 4; ++m)
#pragma unroll
                for (int n = 0; n < 4; ++n)
                    acc[m][n] = __builtin_amdgcn_mfma_f32_16x16x32_bf16(a[m], b[n], acc[m][n], 0, 0, 0);
        }
        __syncthreads();
    }

    int row0 = blockIdx.y * 128 + wr * 64;
    int col0 = blockIdx.x * 128 + wc * 64;
#pragma unroll
    for (int m = 0; m < 4; ++m) {
#pragma unroll
        for (int q = 0; q < 4; ++q) {
            int row = row0 + m * 16 + (lane >> 4) * 4 + q;
            if (row < M) {
#pragma unroll
                for (int n = 0; n < 4; ++n) {
                    int col = col0 + n * 16 + (lane & 15);
                    Cb[(long long)row * N + col] = f2bf(acc[m][n][q]);
                }
            }
        }
    }
}

// ---------------------------------------------------------------------------
// CSR gather aggregation, bf16 input. One wave per node.
// out[i,:] = h[i,:]/deg[i] + sum_p csr_norm[p] * h[csr_src[p],:]
// OUT_TILED: write bf16 tiled+swizzled (feeds GEMM2); else fp32 row-major.
// ---------------------------------------------------------------------------
template <int F, bool RELU, bool OUT_TILED>
__global__ __launch_bounds__(256) void k_gather(const int* __restrict__ csr_src,
                                                const float* __restrict__ csr_norm,
                                                const int* __restrict__ row_ptr,
                                                const short* __restrict__ hb,
                                                const float* __restrict__ deg,
                                                void* __restrict__ outp,
                                                int n_waves) {
    const int FPT = F / 64;  // 8 (F=512) or 4 (F=256)
    int wave = (int)((blockIdx.x * (long long)blockDim.x + threadIdx.x) >> 6);
    if (wave >= n_waves) return;
    int lane = threadIdx.x & 63;

    float acc[FPT];
#pragma unroll
    for (int j = 0; j < FPT; j++) acc[j] = 0.f;

    if (wave < N_NODES) {
        float inv = 1.0f / deg[wave];
        const short* self = &hb[(long long)wave * F + lane * FPT];
        if constexpr (FPT == 8) {
            s8v v = *(const s8v*)self;
#pragma unroll
            for (int j = 0; j < 8; j++) acc[j] = bf2f(v[j]) * inv;
        } else {
            s4v v = *(const s4v*)self;
#pragma unroll
            for (int j = 0; j < 4; j++) acc[j] = bf2f(v[j]) * inv;
        }

        int p = row_ptr[wave];
        int p1 = row_ptr[wave + 1];
        for (; p + 1 < p1; p += 2) {
            int s0 = csr_src[p], s1 = csr_src[p + 1];
            float n0 = csr_norm[p], n1 = csr_norm[p + 1];
            const short* h0 = &hb[(long long)s0 * F + lane * FPT];
            const short* h1 = &hb[(long long)s1 * F + lane * FPT];
            if constexpr (FPT == 8) {
                s8v v0 = *(const s8v*)h0;
                s8v v1 = *(const s8v*)h1;
#pragma unroll
                for (int j = 0; j < 8; j++) acc[j] += n0 * bf2f(v0[j]) + n1 * bf2f(v1[j]);
            } else {
                s4v v0 = *(const s4v*)h0;
                s4v v1 = *(const s4v*)h1;
#pragma unroll
                for (int j = 0; j < 4; j++) acc[j] += n0 * bf2f(v0[j]) + n1 * bf2f(v1[j]);
            }
        }
        if (p < p1) {
            int s0 = csr_src[p];
            float n0 = csr_norm[p];
            const short* h0 = &hb[(long long)s0 * F + lane * FPT];
            if constexpr (FPT == 8) {
                s8v v0 = *(const s8v*)h0;
#pragma unroll
                for (int j = 0; j < 8; j++) acc[j] += n0 * bf2f(v0[j]);
            } else {
                s4v v0 = *(const s4v*)h0;
#pragma unroll
                for (int j = 0; j < 4; j++) acc[j] += n0 * bf2f(v0[j]);
            }
        }
        if (RELU) {
#pragma unroll
            for (int j = 0; j < FPT; j++) acc[j] = fmaxf(acc[j], 0.f);
        }
    }

    if constexpr (OUT_TILED) {  // F == 512: bf16 tiled+swizzled
        s8v v;
#pragma unroll
        for (int j = 0; j < 8; j++) v[j] = f2bf(acc[j]);
        int tm = wave >> 7, r = wave & 127, tk = lane >> 3, sc = lane & 7;
        int slot = sc ^ (r & 7);
        char* out = (char*)outp;
        *(s8v*)&out[(((long long)tm * KT + tk) << 14) + r * 128 + slot * 16] = v;
    } else {
        float* out = (float*)outp + (long long)wave * F + lane * FPT;
#pragma unroll
        for (int j = 0; j < FPT; j += 4) {
            *(float4*)&out[j] = make_float4(acc[j], acc[j + 1], acc[j + 2], acc[j + 3]);
        }
    }
}

// ---------------------------------------------------------------------------
extern "C" void kernel_launch(void* const* d_in, const int* in_sizes, int n_in,
                              void* d_out, int out_size, void* d_ws, size_t ws_size,
                              hipStream_t stream) {
    const float* x  = (const float*)d_in[0];                 // [10000, 512]
    const int*   ei = (const int*)d_in[1];                   // [2, 160000]
    const float* w  = (const float*)d_in[2];                 // [160000]
    const float* W1 = (const float*)d_in[3];                 // [512, 512]
    const float* W2 = (const float*)d_in[4];                 // [512, 256]
    float* out = (float*)d_out;                              // [10000, 256]

    const int* src = ei;
    const int* dst = ei + N_EDGES;

    // workspace layout (256B-aligned chunks)
    char* p = (char*)d_ws;
    auto alloc = [&](size_t bytes) {
        char* r = p;
        p += (bytes + 255) & ~(size_t)255;
        return r;
    };
    char*  x_bf   = alloc((size_t)MT * KT * 16384);     // tiled bf16 x
    char*  a1_bf  = alloc((size_t)MT * KT * 16384);     // tiled bf16 agg1
    char*  w1T    = alloc((size_t)4 * KT * 16384);      // tiled bf16 W1^T
    char*  w2T    = alloc((size_t)2 * KT * 16384);      // tiled bf16 W2^T
    short* h1_bf  = (short*)alloc((size_t)N_NODES * 512 * 2);
    short* h2_bf  = (short*)alloc((size_t)N_NODES * 256 * 2);
    float* deg    = (float*)alloc(N_NODES * 4);
    float* csr_nm = (float*)alloc(N_EDGES * 4);
    int*   csr_s  = (int*)alloc(N_EDGES * 4);
    int*   count  = (int*)alloc(N_NODES * 4);
    int*   rowp   = (int*)alloc((N_NODES + 1) * 4);
    int*   cursor = (int*)alloc(N_NODES * 4);

    const int B = 256;

    // ---- build normalization + CSR (by dst) ----
    k_init<<<(N_NODES + B - 1) / B, B, 0, stream>>>(deg, count);
    k_deg_count<<<(N_EDGES + B - 1) / B, B, 0, stream>>>(dst, w, deg, count);
    k_scan<<<1, 1024, 0, stream>>>(count, rowp, cursor);
    k_fill<<<(N_EDGES + B - 1) / B, B, 0, stream>>>(src, dst, w, deg, cursor, csr_s, csr_nm);

    // ---- bf16 conversions ----
    k_cvt_x<<<(M_PAD * 64) / B, B, 0, stream>>>(x, x_bf);
    k_cvt_w<512><<<512 * 64 / B, B, 0, stream>>>(W1, w1T);
    k_cvt_w<256><<<256 * 64 / B, B, 0, stream>>>(W2, w2T);

    // ---- layer 1: h1 = x @ W1 (bf16 MFMA, bf16 out) ----
    k_gemm_bf16<<<dim3(4, MT), 256, 0, stream>>>(x_bf, w1T, h1_bf, N_NODES, 512);
    // agg1 = relu(gather(h1)) -> tiled bf16 (pad rows zeroed)
    k_gather<512, true, true><<<(M_PAD * 64) / B, B, 0, stream>>>(
        csr_s, csr_nm, rowp, h1_bf, deg, a1_bf, M_PAD);

    // ---- layer 2: h2 = agg1 @ W2 ----
    k_gemm_bf16<<<dim3(2, MT), 256, 0, stream>>>(a1_bf, w2T, h2_bf, N_NODES, 256);
    // out = gather(h2) -> fp32
    k_gather<256, false, false><<<(N_NODES * 64) / B, B, 0, stream>>>(
        csr_s, csr_nm, rowp, h2_bf, deg, out, N_NODES);
}

// Round 4
// 112.735 us; speedup vs baseline: 15.6330x; 1.2102x over previous
//
#include <hip/hip_runtime.h>

#define N_NODES 10000
#define N_EDGES 160000
#define M_PAD   10112   // 79 * 128
#define MT      79
#define KT      8       // K = 512 = 8 * 64

typedef short s8v __attribute__((ext_vector_type(8)));
typedef short s4v __attribute__((ext_vector_type(4)));
typedef float f4v __attribute__((ext_vector_type(4)));

__device__ inline short f2bf(float f) {
    unsigned u = __builtin_bit_cast(unsigned, f);
    u += 0x7FFF + ((u >> 16) & 1);   // RTNE
    return (short)(u >> 16);
}
__device__ inline float bf2f(short s) {
    return __builtin_bit_cast(float, ((unsigned)(unsigned short)s) << 16);
}

#define GLD_LDS16(g, l)                                                      \
    __builtin_amdgcn_global_load_lds(                                        \
        (const __attribute__((address_space(1))) unsigned int*)(g),          \
        (__attribute__((address_space(3))) unsigned int*)(l), 16, 0, 0)

// ---------------------------------------------------------------------------
// k_prep: fused independent prep work, dispatched by blockIdx range.
//   [0, 2528)      : x fp32 -> bf16 tiled+swizzled  (1 thread per 16B chunk)
//   [2528, 2656)   : W1^T -> bf16 tiled (512 cols)
//   [2656, 2720)   : W2^T -> bf16 tiled (256 cols)
//   [2720, 2760)   : deg = 1.0, count = 0
// Tile image = 16 KiB: [128 rows][64 k] bf16; chunk (r, slot) holds
// k = (slot ^ (r&7))*8 .. +8.  Buffer: [row_tile][k_tile][16384 B].
// ---------------------------------------------------------------------------
__global__ __launch_bounds__(256) void k_prep(const float* __restrict__ x,
                                              const float* __restrict__ W1,
                                              const float* __restrict__ W2,
                                              char* __restrict__ x_bf,
                                              char* __restrict__ w1T,
                                              char* __restrict__ w2T,
                                              float* __restrict__ deg,
                                              int* __restrict__ count) {
    int bid = blockIdx.x;
    if (bid < 2528) {                       // ---- cvt_x ----
        long long t = (long long)bid * 256 + threadIdx.x;
        int gr = (int)(t >> 6);
        int c  = (int)(t & 63);
        s8v v;
        if (gr < N_NODES) {
            const float* p = &x[(long long)gr * 512 + c * 8];
#pragma unroll
            for (int j = 0; j < 8; j++) v[j] = f2bf(p[j]);
        } else {
#pragma unroll
            for (int j = 0; j < 8; j++) v[j] = 0;
        }
        int r = gr & 127, tm = gr >> 7, tk = c >> 3, sc = c & 7;
        int slot = sc ^ (r & 7);
        *(s8v*)&x_bf[(((long long)tm * KT + tk) << 14) + r * 128 + slot * 16] = v;
    } else if (bid < 2720) {                // ---- cvt_w (W^T tiled) ----
        const float* W;
        char* out;
        int ncols, t;
        if (bid < 2656) { W = W1; out = w1T; ncols = 512; t = (bid - 2528) * 256 + threadIdx.x; }
        else            { W = W2; out = w2T; ncols = 256; t = (bid - 2656) * 256 + threadIdx.x; }
        int n = t >> 6;
        int c = t & 63;
        s8v v;
#pragma unroll
        for (int j = 0; j < 8; j++) v[j] = f2bf(W[(long long)(c * 8 + j) * ncols + n]);
        int r = n & 127, tn = n >> 7, tk = c >> 3, sc = c & 7;
        int slot = sc ^ (r & 7);
        *(s8v*)&out[(((long long)tn * KT + tk) << 14) + r * 128 + slot * 16] = v;
    } else {                                // ---- init deg/count ----
        int i = (bid - 2720) * 256 + threadIdx.x;
        if (i < N_NODES) { deg[i] = 1.0f; count[i] = 0; }
    }
}

// ---------------------------------------------------------------------------
// shfl-based exclusive scan of count[0..N) -> row_ptr[0..N], cursor copy.
// 1024 threads = 16 waves, 10 elements/thread, 2 barriers.
// ---------------------------------------------------------------------------
__global__ __launch_bounds__(1024) void k_scan(const int* __restrict__ count,
                                               int* __restrict__ row_ptr,
                                               int* __restrict__ cursor) {
    __shared__ int wsum[16];
    const int CH = 10;
    int t = threadIdx.x;
    int lane = t & 63, wid = t >> 6;
    int base = t * CH;
    int c[CH];
    int local = 0;
#pragma unroll
    for (int j = 0; j < CH; j++) {
        int i = base + j;
        c[j] = (i < N_NODES) ? count[i] : 0;
        local += c[j];
    }
    // inclusive wave scan of local
    int scan = local;
#pragma unroll
    for (int off = 1; off < 64; off <<= 1) {
        int u = __shfl_up(scan, off);
        if (lane >= off) scan += u;
    }
    if (lane == 63) wsum[wid] = scan;
    __syncthreads();
    if (wid == 0 && lane < 16) {
        int v = wsum[lane];
        int s = v;
#pragma unroll
        for (int off = 1; off < 16; off <<= 1) {
            int u = __shfl_up(s, off);
            if (lane >= off) s += u;
        }
        wsum[lane] = s - v;   // exclusive wave offset
    }
    __syncthreads();
    int excl = scan - local + wsum[wid];
#pragma unroll
    for (int j = 0; j < CH; j++) {
        int i = base + j;
        if (i < N_NODES) {
            row_ptr[i] = excl;
            cursor[i] = excl;
            excl += c[j];
        }
    }
    if (t == 1023) row_ptr[N_NODES] = excl;
}

__global__ void k_fill(const int* __restrict__ src, const int* __restrict__ dst,
                       const float* __restrict__ w, const float* __restrict__ deg,
                       int* __restrict__ cursor, int* __restrict__ csr_src,
                       float* __restrict__ csr_norm) {
    int e = blockIdx.x * blockDim.x + threadIdx.x;
    if (e < N_EDGES) {
        int d = dst[e];
        int s = src[e];
        int pos = atomicAdd(&cursor[d], 1);
        csr_src[pos] = s;
        csr_norm[pos] = rsqrtf(deg[s]) * w[e] * rsqrtf(deg[d]);
    }
}

// ---------------------------------------------------------------------------
// GEMM core (bf16 MFMA, 128x128 tile, BK=64, 4 waves 2x2, swizzled LDS).
// ---------------------------------------------------------------------------
__device__ __forceinline__ void gemm_block(const char* __restrict__ ga,
                                           const char* __restrict__ gb,
                                           short* __restrict__ Cb,
                                           int M, int N, int row_blk, int col_blk,
                                           char* As, char* Bs) {
    int tid = threadIdx.x, lane = tid & 63, w = tid >> 6;
    int wr = w >> 1, wc = w & 1;

    f4v acc[4][4];
#pragma unroll
    for (int m = 0; m < 4; m++)
#pragma unroll
        for (int n = 0; n < 4; n++) acc[m][n] = (f4v){0.f, 0.f, 0.f, 0.f};

    for (int kt = 0; kt < KT; ++kt) {
        const char* a0 = ga + (kt << 14);
        const char* b0 = gb + (kt << 14);
#pragma unroll
        for (int j = 0; j < 4; ++j) {
            int off = (j * 256 + w * 64) * 16;
            GLD_LDS16(a0 + off + lane * 16, As + off);
            GLD_LDS16(b0 + off + lane * 16, Bs + off);
        }
        __syncthreads();

#pragma unroll
        for (int kk = 0; kk < 2; ++kk) {
            s8v a[4], b[4];
#pragma unroll
            for (int m = 0; m < 4; ++m) {
                int r = wr * 64 + m * 16 + (lane & 15);
                int slot = ((lane >> 4) + kk * 4) ^ (r & 7);
                a[m] = *(const s8v*)&As[r * 128 + slot * 16];
            }
#pragma unroll
            for (int n = 0; n < 4; ++n) {
                int r = wc * 64 + n * 16 + (lane & 15);
                int slot = ((lane >> 4) + kk * 4) ^ (r & 7);
                b[n] = *(const s8v*)&Bs[r * 128 + slot * 16];
            }
#pragma unroll
            for (int m = 0; m < 4; ++m)
#pragma unroll
                for (int n = 0; n < 4; ++n)
                    acc[m][n] = __builtin_amdgcn_mfma_f32_16x16x32_bf16(a[m], b[n], acc[m][n], 0, 0, 0);
        }
        __syncthreads();
    }

    int row0 = row_blk * 128 + wr * 64;
    int col0 = col_blk * 128 + wc * 64;
#pragma unroll
    for (int m = 0; m < 4; ++m) {
#pragma unroll
        for (int q = 0; q < 4; ++q) {
            int row = row0 + m * 16 + (lane >> 4) * 4 + q;
            if (row < M) {
#pragma unroll
                for (int n = 0; n < 4; ++n) {
                    int col = col0 + n * 16 + (lane & 15);
                    Cb[(long long)row * N + col] = f2bf(acc[m][n][q]);
                }
            }
        }
    }
}

// layer-1 GEMM (316 blocks) + fused deg/count accumulation (625 blocks)
__global__ __launch_bounds__(256) void k_gemm1_deg(const char* __restrict__ A,
                                                   const char* __restrict__ B,
                                                   short* __restrict__ Cb,
                                                   const int* __restrict__ dst,
                                                   const float* __restrict__ wgt,
                                                   float* __restrict__ deg,
                                                   int* __restrict__ count) {
    int bid = blockIdx.x;
    if (bid >= 316) {
        int e = (bid - 316) * 256 + threadIdx.x;
        if (e < N_EDGES) {
            int d = dst[e];
            atomicAdd(&deg[d], wgt[e]);
            atomicAdd(&count[d], 1);
        }
        return;
    }
    __shared__ char As[16384];
    __shared__ char Bs[16384];
    int bx = bid & 3, by = bid >> 2;
    gemm_block(A + ((long long)by * KT << 14), B + ((long long)bx * KT << 14),
               Cb, N_NODES, 512, by, bx, As, Bs);
}

// plain GEMM for layer 2
__global__ __launch_bounds__(256) void k_gemm_bf16(const char* __restrict__ A,
                                                   const char* __restrict__ B,
                                                   short* __restrict__ Cb,
                                                   int M, int N) {
    __shared__ char As[16384];
    __shared__ char Bs[16384];
    gemm_block(A + ((long long)blockIdx.y * KT << 14),
               B + ((long long)blockIdx.x * KT << 14),
               Cb, M, N, blockIdx.y, blockIdx.x, As, Bs);
}

// ---------------------------------------------------------------------------
// CSR gather aggregation, bf16 input. One wave per node, 4-edge unroll.
// ---------------------------------------------------------------------------
template <int F, bool RELU, bool OUT_TILED>
__global__ __launch_bounds__(256) void k_gather(const int* __restrict__ csr_src,
                                                const float* __restrict__ csr_norm,
                                                const int* __restrict__ row_ptr,
                                                const short* __restrict__ hb,
                                                const float* __restrict__ deg,
                                                void* __restrict__ outp,
                                                int n_waves) {
    const int FPT = F / 64;  // 8 (F=512) or 4 (F=256)
    int wave = (int)((blockIdx.x * (long long)blockDim.x + threadIdx.x) >> 6);
    if (wave >= n_waves) return;
    int lane = threadIdx.x & 63;

    float acc[FPT];
#pragma unroll
    for (int j = 0; j < FPT; j++) acc[j] = 0.f;

    if (wave < N_NODES) {
        float inv = 1.0f / deg[wave];
        const short* self = &hb[(long long)wave * F + lane * FPT];
        if constexpr (FPT == 8) {
            s8v v = *(const s8v*)self;
#pragma unroll
            for (int j = 0; j < 8; j++) acc[j] = bf2f(v[j]) * inv;
        } else {
            s4v v = *(const s4v*)self;
#pragma unroll
            for (int j = 0; j < 4; j++) acc[j] = bf2f(v[j]) * inv;
        }

        int p = row_ptr[wave];
        int p1 = row_ptr[wave + 1];
        for (; p + 3 < p1; p += 4) {
            int s0 = csr_src[p], s1 = csr_src[p + 1], s2 = csr_src[p + 2], s3 = csr_src[p + 3];
            float n0 = csr_norm[p], n1 = csr_norm[p + 1], n2 = csr_norm[p + 2], n3 = csr_norm[p + 3];
            if constexpr (FPT == 8) {
                s8v v0 = *(const s8v*)&hb[(long long)s0 * F + lane * 8];
                s8v v1 = *(const s8v*)&hb[(long long)s1 * F + lane * 8];
                s8v v2 = *(const s8v*)&hb[(long long)s2 * F + lane * 8];
                s8v v3 = *(const s8v*)&hb[(long long)s3 * F + lane * 8];
#pragma unroll
                for (int j = 0; j < 8; j++)
                    acc[j] += n0 * bf2f(v0[j]) + n1 * bf2f(v1[j]) + n2 * bf2f(v2[j]) + n3 * bf2f(v3[j]);
            } else {
                s4v v0 = *(const s4v*)&hb[(long long)s0 * F + lane * 4];
                s4v v1 = *(const s4v*)&hb[(long long)s1 * F + lane * 4];
                s4v v2 = *(const s4v*)&hb[(long long)s2 * F + lane * 4];
                s4v v3 = *(const s4v*)&hb[(long long)s3 * F + lane * 4];
#pragma unroll
                for (int j = 0; j < 4; j++)
                    acc[j] += n0 * bf2f(v0[j]) + n1 * bf2f(v1[j]) + n2 * bf2f(v2[j]) + n3 * bf2f(v3[j]);
            }
        }
        for (; p < p1; ++p) {
            int s0 = csr_src[p];
            float n0 = csr_norm[p];
            if constexpr (FPT == 8) {
                s8v v0 = *(const s8v*)&hb[(long long)s0 * F + lane * 8];
#pragma unroll
                for (int j = 0; j < 8; j++) acc[j] += n0 * bf2f(v0[j]);
            } else {
                s4v v0 = *(const s4v*)&hb[(long long)s0 * F + lane * 4];
#pragma unroll
                for (int j = 0; j < 4; j++) acc[j] += n0 * bf2f(v0[j]);
            }
        }
        if (RELU) {
#pragma unroll
            for (int j = 0; j < FPT; j++) acc[j] = fmaxf(acc[j], 0.f);
        }
    }

    if constexpr (OUT_TILED) {  // F == 512: bf16 tiled+swizzled
        s8v v;
#pragma unroll
        for (int j = 0; j < 8; j++) v[j] = f2bf(acc[j]);
        int tm = wave >> 7, r = wave & 127, tk = lane >> 3, sc = lane & 7;
        int slot = sc ^ (r & 7);
        char* out = (char*)outp;
        *(s8v*)&out[(((long long)tm * KT + tk) << 14) + r * 128 + slot * 16] = v;
    } else {
        float* out = (float*)outp + (long long)wave * F + lane * FPT;
#pragma unroll
        for (int j = 0; j < FPT; j += 4) {
            *(float4*)&out[j] = make_float4(acc[j], acc[j + 1], acc[j + 2], acc[j + 3]);
        }
    }
}

// ---------------------------------------------------------------------------
extern "C" void kernel_launch(void* const* d_in, const int* in_sizes, int n_in,
                              void* d_out, int out_size, void* d_ws, size_t ws_size,
                              hipStream_t stream) {
    const float* x  = (const float*)d_in[0];                 // [10000, 512]
    const int*   ei = (const int*)d_in[1];                   // [2, 160000]
    const float* w  = (const float*)d_in[2];                 // [160000]
    const float* W1 = (const float*)d_in[3];                 // [512, 512]
    const float* W2 = (const float*)d_in[4];                 // [512, 256]
    float* out = (float*)d_out;                              // [10000, 256]

    const int* src = ei;
    const int* dst = ei + N_EDGES;

    char* p = (char*)d_ws;
    auto alloc = [&](size_t bytes) {
        char* r = p;
        p += (bytes + 255) & ~(size_t)255;
        return r;
    };
    char*  x_bf   = alloc((size_t)MT * KT * 16384);
    char*  a1_bf  = alloc((size_t)MT * KT * 16384);
    char*  w1T    = alloc((size_t)4 * KT * 16384);
    char*  w2T    = alloc((size_t)2 * KT * 16384);
    short* h1_bf  = (short*)alloc((size_t)N_NODES * 512 * 2);
    short* h2_bf  = (short*)alloc((size_t)N_NODES * 256 * 2);
    float* deg    = (float*)alloc(N_NODES * 4);
    float* csr_nm = (float*)alloc(N_EDGES * 4);
    int*   csr_s  = (int*)alloc(N_EDGES * 4);
    int*   count  = (int*)alloc(N_NODES * 4);
    int*   rowp   = (int*)alloc((N_NODES + 1) * 4);
    int*   cursor = (int*)alloc(N_NODES * 4);

    const int B = 256;

    // 1. fused prep: cvt_x + cvt_w1 + cvt_w2 + init deg/count
    k_prep<<<2760, B, 0, stream>>>(x, W1, W2, x_bf, w1T, w2T, deg, count);
    // 2. layer-1 GEMM + deg/count accumulation
    k_gemm1_deg<<<316 + 625, B, 0, stream>>>(x_bf, w1T, h1_bf, dst, w, deg, count);
    // 3. scan -> row_ptr / cursor
    k_scan<<<1, 1024, 0, stream>>>(count, rowp, cursor);
    // 4. fill CSR (norm needs deg; cursor needs scan)
    k_fill<<<(N_EDGES + B - 1) / B, B, 0, stream>>>(src, dst, w, deg, cursor, csr_s, csr_nm);
    // 5. agg1 = relu(gather(h1)) -> tiled bf16
    k_gather<512, true, true><<<(M_PAD * 64) / B, B, 0, stream>>>(
        csr_s, csr_nm, rowp, h1_bf, deg, a1_bf, M_PAD);
    // 6. layer-2 GEMM
    k_gemm_bf16<<<dim3(2, MT), B, 0, stream>>>(a1_bf, w2T, h2_bf, N_NODES, 256);
    // 7. out = gather(h2) -> fp32
    k_gather<256, false, false><<<(N_NODES * 64) / B, B, 0, stream>>>(
        csr_s, csr_nm, rowp, h2_bf, deg, out, N_NODES);
}